// Round 11
// baseline (858.313 us; speedup 1.0000x reference)
//
#include <hip/hip_runtime.h>

// GAT aggregate, two-phase — R11 PROBE ROUND.
//   Phase 1 (ctx_kernel): ctx -> d_ws  (R5-exact code, new destination)
//   Phase 2 (mlp_mfma):   d_out = relu(ctx @ W)  (R10-exact, OUT-OF-PLACE)
//                         launched 9x (idempotent) to measure t_mlp by
//                         amplified subtraction: T11 - 267.5 ~= 8*t_mlp.
// Rationale: R9 (VALU) and R10 (MFMA) phase-2 kernels differ structurally yet
// both subtract to ~104us, and neither matches a ~25us model -> either a
// hidden ~100us phase-2 cost, or the R8 subtraction baseline (ctx=164us) is
// wrong and ctx is really ~240us standalone. This probe separates the cases.
// Fallback: if ws_size is too small, run R10's in-place path (deterministic).

constexpr int K    = 16;
constexpr int D    = 128;
constexpr int DOUT = 128;
constexpr int WT_PITCH = 136;   // 128 + 8 pad (shorts) = 272B rows

typedef short bfrag  __attribute__((ext_vector_type(8)));
typedef float afrag  __attribute__((ext_vector_type(4)));

__device__ __forceinline__ unsigned short f2bf(float f) {
    union { float f; unsigned u; } v; v.f = f;
    const unsigned r = v.u + 0x7FFF + ((v.u >> 16) & 1);   // RNE
    return (unsigned short)(r >> 16);
}
__device__ __forceinline__ float bf2f(unsigned short b) {
    union { unsigned u; float f; } v; v.u = ((unsigned)b) << 16;
    return v.f;
}

__device__ __forceinline__ float wave_allsum(float x) {
    #pragma unroll
    for (int off = 32; off; off >>= 1)
        x += __shfl_xor(x, off);
    return x;
}

// ---------------- Phase 1: attention context (R5-exact) ----------------
__launch_bounds__(256, 4)
__global__ void ctx_kernel(const float* __restrict__ self_vecs,
                           const float* __restrict__ neigh_vecs,
                           float* __restrict__ ctx_out,
                           int n_nodes) {
    const int lane = threadIdx.x & 63;
    const int n = (int)((blockIdx.x * blockDim.x + threadIdx.x) >> 6);
    if (n >= n_nodes) return;

    const float* nbp = neigh_vecs + (size_t)n * (K * D) + 2 * lane;
    float2 v[K];
    #pragma unroll
    for (int k = 0; k < K; ++k) v[k] = *(const float2*)(nbp + (size_t)k * D);
    const float2 s = *(const float2*)(self_vecs + (size_t)n * D + 2 * lane);

    float m = wave_allsum(s.x * s.x + s.y * s.y);
    float sum = 1.f, cx = s.x, cy = s.y;
    #pragma unroll
    for (int k = 0; k < K; ++k) {
        const float d  = wave_allsum(s.x * v[k].x + s.y * v[k].y);
        const float mn = fmaxf(m, d);
        const float sc = __expf(m - mn);
        const float e  = __expf(d - mn);
        sum = sum * sc + e;
        cx  = cx * sc + e * v[k].x;
        cy  = cy * sc + e * v[k].y;
        m = mn;
    }
    const float inv = 1.f / sum;
    *(float2*)(ctx_out + (size_t)n * D + 2 * lane) = make_float2(cx * inv, cy * inv);
}

// ---------------- Phase 2: row MLP via bf16 MFMA (R10-exact, out-of-place) ----------------
__launch_bounds__(256, 4)
__global__ void mlp_mfma(const float* __restrict__ W,
                         const float* __restrict__ ctx,
                         float* __restrict__ outp,
                         int n_tiles, int total_waves) {
    __shared__ __align__(16) unsigned short Wt[DOUT][WT_PITCH];

    const int tid = threadIdx.x;
    for (int e = tid; e < D * DOUT; e += blockDim.x) {
        const int k = e >> 7, m = e & 127;     // W row-major [k][dout]
        Wt[m][k] = f2bf(W[e]);
    }
    __syncthreads();

    const int lane = tid & 63;
    const int nl   = lane & 15;   // node-in-tile / A row-in-tile
    const int kb   = lane >> 4;   // k-subgroup (8 elems each)
    const int wave = blockIdx.x * (blockDim.x >> 6) + (tid >> 6);

    for (int t = wave; t < n_tiles; t += total_waves) {
        const int node0 = t * 16;
        afrag acc[8];
        #pragma unroll
        for (int i = 0; i < 8; ++i)
            #pragma unroll
            for (int r = 0; r < 4; ++r) acc[i][r] = 0.f;

        #pragma unroll
        for (int kc = 0; kc < 4; ++kc) {
            const float* cp = ctx + (size_t)(node0 + nl) * D + kc * 32 + kb * 8;
            const float4 c0 = *(const float4*)cp;
            const float4 c1 = *(const float4*)(cp + 4);
            const float cf[8] = {c0.x, c0.y, c0.z, c0.w, c1.x, c1.y, c1.z, c1.w};
            bfrag ch, cl;
            #pragma unroll
            for (int i = 0; i < 8; ++i) {
                const unsigned short h = f2bf(cf[i]);
                ch[i] = (short)h;
                cl[i] = (short)f2bf(cf[i] - bf2f(h));
            }
            #pragma unroll
            for (int nt = 0; nt < 8; ++nt) {
                const bfrag a = *(const bfrag*)&Wt[nt * 16 + nl][kc * 32 + kb * 8];
                acc[nt] = __builtin_amdgcn_mfma_f32_16x16x32_bf16(a, ch, acc[nt], 0, 0, 0);
                acc[nt] = __builtin_amdgcn_mfma_f32_16x16x32_bf16(a, cl, acc[nt], 0, 0, 0);
            }
        }
        float* orow = outp + (size_t)(node0 + nl) * DOUT + kb * 4;
        #pragma unroll
        for (int nt = 0; nt < 8; ++nt) {
            const float4 v = make_float4(fmaxf(acc[nt][0], 0.f), fmaxf(acc[nt][1], 0.f),
                                         fmaxf(acc[nt][2], 0.f), fmaxf(acc[nt][3], 0.f));
            *(float4*)(orow + nt * 16) = v;
        }
    }
}

extern "C" void kernel_launch(void* const* d_in, const int* in_sizes, int n_in,
                              void* d_out, int out_size, void* d_ws, size_t ws_size,
                              hipStream_t stream) {
    const float* self_vecs = (const float*)d_in[0];
    const float* neigh     = (const float*)d_in[1];
    const float* W         = (const float*)d_in[2];
    float* io = (float*)d_out;

    const int n_nodes = in_sizes[0] / D;   // 100000
    const int n_tiles = n_nodes / 16;      // 6250 exact
    const size_t ctx_bytes = (size_t)n_nodes * D * sizeof(float);

    const int tpb1 = 256;
    const int blocks1 = (n_nodes * 64 + tpb1 - 1) / tpb1;  // 25000
    const int tpb2 = 256;
    const int blocks2 = 1024;
    const int total_waves2 = blocks2 * (tpb2 / 64);

    if (ws_size >= ctx_bytes) {
        float* cbuf = (float*)d_ws;
        ctx_kernel<<<dim3(blocks1), dim3(tpb1), 0, stream>>>(
            self_vecs, neigh, cbuf, n_nodes);
        // PROBE: 9 idempotent launches; T11 - 267.5 ~= 8 * t_mlp
        for (int rep = 0; rep < 9; ++rep)
            mlp_mfma<<<dim3(blocks2), dim3(tpb2), 0, stream>>>(
                W, cbuf, io, n_tiles, total_waves2);
    } else {
        // fallback: R10 in-place path (ctx lives in d_out)
        ctx_kernel<<<dim3(blocks1), dim3(tpb1), 0, stream>>>(
            self_vecs, neigh, io, n_nodes);
        mlp_mfma<<<dim3(blocks2), dim3(tpb2), 0, stream>>>(
            W, io, io, n_tiles, total_waves2);
    }
}

// Round 12
// 230.035 us; speedup vs baseline: 3.7312x; 3.7312x over previous
//
#include <hip/hip_runtime.h>

// GAT aggregate, FUSED (R12): N=100000, K=16, D=128, DOUT=128, fp32.
// Per 16-node tile, one 256-thr block: 4 waves compute 4 ctx rows each
// (R5-verbatim online-softmax body) into LDS Ct[buf], one barrier, then each
// wave runs the R10-verified bf16-MFMA path (2 of 8 nt output subtiles) from
// LDS straight to d_out. Kills the 102MB ctx round-trip, the second launch,
// and phase-2's scattered global reads (R11 probe: mlp=74us vs 16us floor).
// Ct double-buffered -> ONE barrier per tile. LDS 34.8K(Wt)+16.5K(Ct)=51.3K
// -> 3 blocks/CU, 12 waves/CU. 100000 = 6250 exact tiles.

constexpr int K    = 16;
constexpr int D    = 128;
constexpr int DOUT = 128;
constexpr int WT_PITCH = 136;   // bf16 Wt row pitch (shorts), 272B rows
constexpr int CT_PITCH = 132;   // f32 Ct row pitch (floats), 528B rows

typedef short bfrag  __attribute__((ext_vector_type(8)));
typedef float afrag  __attribute__((ext_vector_type(4)));

__device__ __forceinline__ unsigned short f2bf(float f) {
    union { float f; unsigned u; } v; v.f = f;
    const unsigned r = v.u + 0x7FFF + ((v.u >> 16) & 1);   // RNE
    return (unsigned short)(r >> 16);
}
__device__ __forceinline__ float bf2f(unsigned short b) {
    union { unsigned u; float f; } v; v.u = ((unsigned)b) << 16;
    return v.f;
}

__device__ __forceinline__ float wave_allsum(float x) {
    #pragma unroll
    for (int off = 32; off; off >>= 1)
        x += __shfl_xor(x, off);
    return x;
}

__launch_bounds__(256, 3)
__global__ void gat_fused(const float* __restrict__ self_vecs,
                          const float* __restrict__ neigh_vecs,
                          const float* __restrict__ W,
                          float* __restrict__ out,
                          int n_tiles) {
    __shared__ __align__(16) unsigned short Wt[DOUT][WT_PITCH];   // 34.8 KiB
    __shared__ __align__(16) float Ct[2][16][CT_PITCH];           // 16.5 KiB

    const int tid = threadIdx.x;

    // ---- stage W^T as bf16 (R10-verbatim) ----
    for (int e = tid; e < D * DOUT; e += blockDim.x) {
        const int k = e >> 7, m = e & 127;     // W row-major [k][dout]
        Wt[m][k] = f2bf(W[e]);
    }
    __syncthreads();

    const int lane = tid & 63;
    const int wid  = tid >> 6;
    const int nl   = lane & 15;   // node-in-tile / Wt row-in-subtile
    const int kb   = lane >> 4;   // k-subgroup (8 elems)

    int buf = 0;
    for (int t = blockIdx.x; t < n_tiles; t += gridDim.x, buf ^= 1) {
        const int node0 = t * 16;

        // ---- ctx for 4 nodes per wave (R5-verbatim body) -> Ct[buf] ----
        #pragma unroll
        for (int i = 0; i < 4; ++i) {
            const int r = wid * 4 + i;           // row in tile
            const int n = node0 + r;
            const float* nbp = neigh_vecs + (size_t)n * (K * D) + 2 * lane;
            float2 v[K];
            #pragma unroll
            for (int k = 0; k < K; ++k) v[k] = *(const float2*)(nbp + (size_t)k * D);
            const float2 s = *(const float2*)(self_vecs + (size_t)n * D + 2 * lane);

            float m = wave_allsum(s.x * s.x + s.y * s.y);
            float sum = 1.f, cx = s.x, cy = s.y;
            #pragma unroll
            for (int k = 0; k < K; ++k) {
                const float d  = wave_allsum(s.x * v[k].x + s.y * v[k].y);
                const float mn = fmaxf(m, d);
                const float sc = __expf(m - mn);
                const float e  = __expf(d - mn);
                sum = sum * sc + e;
                cx  = cx * sc + e * v[k].x;
                cy  = cy * sc + e * v[k].y;
                m = mn;
            }
            const float inv = 1.f / sum;
            *(float2*)&Ct[buf][r][2 * lane] = make_float2(cx * inv, cy * inv);
        }
        __syncthreads();   // Ct[buf] complete; dbuf makes this the ONLY barrier

        // ---- MFMA (R10-verbatim layouts): this wave does nt = wid*2, wid*2+1 ----
        afrag acc[2];
        #pragma unroll
        for (int h = 0; h < 2; ++h)
            #pragma unroll
            for (int r4 = 0; r4 < 4; ++r4) acc[h][r4] = 0.f;

        #pragma unroll
        for (int kc = 0; kc < 4; ++kc) {
            const float* cp = &Ct[buf][nl][kc * 32 + kb * 8];
            const float4 c0 = *(const float4*)cp;
            const float4 c1 = *(const float4*)(cp + 4);
            const float cf[8] = {c0.x, c0.y, c0.z, c0.w, c1.x, c1.y, c1.z, c1.w};
            bfrag ch, cl;
            #pragma unroll
            for (int i = 0; i < 8; ++i) {
                const unsigned short hh = f2bf(cf[i]);
                ch[i] = (short)hh;
                cl[i] = (short)f2bf(cf[i] - bf2f(hh));
            }
            #pragma unroll
            for (int h = 0; h < 2; ++h) {
                const int nt = wid * 2 + h;
                const bfrag a = *(const bfrag*)&Wt[nt * 16 + nl][kc * 32 + kb * 8];
                acc[h] = __builtin_amdgcn_mfma_f32_16x16x32_bf16(a, ch, acc[h], 0, 0, 0);
                acc[h] = __builtin_amdgcn_mfma_f32_16x16x32_bf16(a, cl, acc[h], 0, 0, 0);
            }
        }
        // D: col=lane&15=node, row=(lane>>4)*4+r=outcol (m89-verified)
        float* orow = out + (size_t)(node0 + nl) * DOUT + kb * 4;
        #pragma unroll
        for (int h = 0; h < 2; ++h) {
            const int nt = wid * 2 + h;
            *(float4*)(orow + nt * 16) =
                make_float4(fmaxf(acc[h][0], 0.f), fmaxf(acc[h][1], 0.f),
                            fmaxf(acc[h][2], 0.f), fmaxf(acc[h][3], 0.f));
        }
    }
}

extern "C" void kernel_launch(void* const* d_in, const int* in_sizes, int n_in,
                              void* d_out, int out_size, void* d_ws, size_t ws_size,
                              hipStream_t stream) {
    const float* self_vecs = (const float*)d_in[0];
    const float* neigh     = (const float*)d_in[1];
    const float* W         = (const float*)d_in[2];
    float* out = (float*)d_out;

    const int n_nodes = in_sizes[0] / D;   // 100000
    const int n_tiles = n_nodes / 16;      // 6250 exact (no remainder for this problem)

    const int tpb = 256;     // 4 waves
    const int blocks = 768;  // 3 blocks/CU x 256 CU (51.3 KiB LDS each)
    gat_fused<<<dim3(blocks), dim3(tpb), 0, stream>>>(
        self_vecs, neigh, W, out, n_tiles);
}

// Round 13
// 228.113 us; speedup vs baseline: 3.7627x; 1.0084x over previous
//
#include <hip/hip_runtime.h>

// GAT aggregate, FUSED (R13 = R12 + two-pass softmax): N=100000, K=16, D=128,
// DOUT=128, fp32. Per 16-node tile, one 256-thr block: 4 waves compute 4 ctx
// rows each into LDS Ct[buf], one barrier, then the R10-verified bf16-MFMA
// path (2 of 8 nt subtiles per wave) from LDS straight to d_out.
//
// R13 change (ctx body ONLY): online softmax -> two-pass softmax (R1-proven
// numerics). The 17 butterfly reduction chains become INDEPENDENT and
// pipeline on the DS pipe (~500cyc issue-bound) instead of a serial
// 16x170cyc online-update chain. Load duty cycle per wave rises ~25%->55%,
// which is what capped ctx at 4.8 TB/s (R11 probe: ctx=193us standalone).

constexpr int K    = 16;
constexpr int D    = 128;
constexpr int DOUT = 128;
constexpr int WT_PITCH = 136;   // bf16 Wt row pitch (shorts), 272B rows
constexpr int CT_PITCH = 132;   // f32 Ct row pitch (floats), 528B rows

typedef short bfrag  __attribute__((ext_vector_type(8)));
typedef float afrag  __attribute__((ext_vector_type(4)));

__device__ __forceinline__ unsigned short f2bf(float f) {
    union { float f; unsigned u; } v; v.f = f;
    const unsigned r = v.u + 0x7FFF + ((v.u >> 16) & 1);   // RNE
    return (unsigned short)(r >> 16);
}
__device__ __forceinline__ float bf2f(unsigned short b) {
    union { unsigned u; float f; } v; v.u = ((unsigned)b) << 16;
    return v.f;
}

__device__ __forceinline__ float wave_allsum(float x) {
    #pragma unroll
    for (int off = 32; off; off >>= 1)
        x += __shfl_xor(x, off);
    return x;
}

__launch_bounds__(256, 3)
__global__ void gat_fused(const float* __restrict__ self_vecs,
                          const float* __restrict__ neigh_vecs,
                          const float* __restrict__ W,
                          float* __restrict__ out,
                          int n_tiles) {
    __shared__ __align__(16) unsigned short Wt[DOUT][WT_PITCH];   // 34.8 KiB
    __shared__ __align__(16) float Ct[2][16][CT_PITCH];           // 16.5 KiB

    const int tid = threadIdx.x;

    // ---- stage W^T as bf16 (R10-verbatim) ----
    for (int e = tid; e < D * DOUT; e += blockDim.x) {
        const int k = e >> 7, m = e & 127;     // W row-major [k][dout]
        Wt[m][k] = f2bf(W[e]);
    }
    __syncthreads();

    const int lane = tid & 63;
    const int wid  = tid >> 6;
    const int nl   = lane & 15;   // node-in-tile / Wt row-in-subtile
    const int kb   = lane >> 4;   // k-subgroup (8 elems)

    int buf = 0;
    for (int t = blockIdx.x; t < n_tiles; t += gridDim.x, buf ^= 1) {
        const int node0 = t * 16;

        // ---- ctx for 4 nodes per wave (two-pass softmax) -> Ct[buf] ----
        #pragma unroll
        for (int i = 0; i < 4; ++i) {
            const int r = wid * 4 + i;           // row in tile
            const int n = node0 + r;
            const float* nbp = neigh_vecs + (size_t)n * (K * D) + 2 * lane;
            float2 v[K];
            #pragma unroll
            for (int k = 0; k < K; ++k) v[k] = *(const float2*)(nbp + (size_t)k * D);
            const float2 s = *(const float2*)(self_vecs + (size_t)n * D + 2 * lane);

            // pass 1: all 17 dot-reductions, independent -> DS pipe pipelines them
            float ss = s.x * s.x + s.y * s.y;
            float sc[K];
            #pragma unroll
            for (int k = 0; k < K; ++k) sc[k] = s.x * v[k].x + s.y * v[k].y;
            ss = wave_allsum(ss);
            #pragma unroll
            for (int k = 0; k < K; ++k) sc[k] = wave_allsum(sc[k]);

            // pass 2: stable softmax + weighted sum (R1-proven numerics)
            float m = ss;
            #pragma unroll
            for (int k = 0; k < K; ++k) m = fmaxf(m, sc[k]);
            float e  = __expf(ss - m);
            float sum = e, cx = e * s.x, cy = e * s.y;
            #pragma unroll
            for (int k = 0; k < K; ++k) {
                const float ek = __expf(sc[k] - m);
                sum += ek;
                cx  += ek * v[k].x;
                cy  += ek * v[k].y;
            }
            const float inv = 1.f / sum;
            *(float2*)&Ct[buf][r][2 * lane] = make_float2(cx * inv, cy * inv);
        }
        __syncthreads();   // Ct[buf] complete; dbuf makes this the ONLY barrier

        // ---- MFMA (R10-verbatim layouts): this wave does nt = wid*2, wid*2+1 ----
        afrag acc[2];
        #pragma unroll
        for (int h = 0; h < 2; ++h)
            #pragma unroll
            for (int r4 = 0; r4 < 4; ++r4) acc[h][r4] = 0.f;

        #pragma unroll
        for (int kc = 0; kc < 4; ++kc) {
            const float* cp = &Ct[buf][nl][kc * 32 + kb * 8];
            const float4 c0 = *(const float4*)cp;
            const float4 c1 = *(const float4*)(cp + 4);
            const float cf[8] = {c0.x, c0.y, c0.z, c0.w, c1.x, c1.y, c1.z, c1.w};
            bfrag ch, cl;
            #pragma unroll
            for (int i = 0; i < 8; ++i) {
                const unsigned short hh = f2bf(cf[i]);
                ch[i] = (short)hh;
                cl[i] = (short)f2bf(cf[i] - bf2f(hh));
            }
            #pragma unroll
            for (int h = 0; h < 2; ++h) {
                const int nt = wid * 2 + h;
                const bfrag a = *(const bfrag*)&Wt[nt * 16 + nl][kc * 32 + kb * 8];
                acc[h] = __builtin_amdgcn_mfma_f32_16x16x32_bf16(a, ch, acc[h], 0, 0, 0);
                acc[h] = __builtin_amdgcn_mfma_f32_16x16x32_bf16(a, cl, acc[h], 0, 0, 0);
            }
        }
        // D: col=lane&15=node, row=(lane>>4)*4+r=outcol (m89-verified)
        float* orow = out + (size_t)(node0 + nl) * DOUT + kb * 4;
        #pragma unroll
        for (int h = 0; h < 2; ++h) {
            const int nt = wid * 2 + h;
            *(float4*)(orow + nt * 16) =
                make_float4(fmaxf(acc[h][0], 0.f), fmaxf(acc[h][1], 0.f),
                            fmaxf(acc[h][2], 0.f), fmaxf(acc[h][3], 0.f));
        }
    }
}

extern "C" void kernel_launch(void* const* d_in, const int* in_sizes, int n_in,
                              void* d_out, int out_size, void* d_ws, size_t ws_size,
                              hipStream_t stream) {
    const float* self_vecs = (const float*)d_in[0];
    const float* neigh     = (const float*)d_in[1];
    const float* W         = (const float*)d_in[2];
    float* out = (float*)d_out;

    const int n_nodes = in_sizes[0] / D;   // 100000
    const int n_tiles = n_nodes / 16;      // 6250 exact

    const int tpb = 256;     // 4 waves
    const int blocks = 768;  // 3 blocks/CU x 256 CU (51.3 KiB LDS each)
    gat_fused<<<dim3(blocks), dim3(tpb), 0, stream>>>(
        self_vecs, neigh, W, out, n_tiles);
}

// Round 14
// 211.677 us; speedup vs baseline: 4.0548x; 1.0776x over previous
//
#include <hip/hip_runtime.h>

// GAT aggregate, FUSED (R14 = R13 + depth-2 load pipeline): N=100000, K=16,
// D=128, DOUT=128, fp32. Per 16-node tile, one 256-thr block: 4 waves x 4 ctx
// rows -> LDS Ct[buf], one barrier, R10-verified bf16-MFMA epilogue to d_out.
//
// R14 change (load scheduling ONLY): ping-pong register buffers vA/vB so each
// node's 17 HBM loads are issued BEFORE the previous node's softmax compute,
// and the next TILE's first two nodes are issued before the MFMA phase.
// Theory: R13 null showed the limiter is load-issue duty (~60%: loads stall
// behind compute + MFMA bubble), not chain depth. This lifts duty to ~90%.

constexpr int K    = 16;
constexpr int D    = 128;
constexpr int DOUT = 128;
constexpr int WT_PITCH = 136;   // bf16 Wt row pitch (shorts), 272B rows
constexpr int CT_PITCH = 132;   // f32 Ct row pitch (floats), 528B rows

typedef short bfrag  __attribute__((ext_vector_type(8)));
typedef float afrag  __attribute__((ext_vector_type(4)));

__device__ __forceinline__ unsigned short f2bf(float f) {
    union { float f; unsigned u; } v; v.f = f;
    const unsigned r = v.u + 0x7FFF + ((v.u >> 16) & 1);   // RNE
    return (unsigned short)(r >> 16);
}
__device__ __forceinline__ float bf2f(unsigned short b) {
    union { unsigned u; float f; } v; v.u = ((unsigned)b) << 16;
    return v.f;
}

__device__ __forceinline__ float wave_allsum(float x) {
    #pragma unroll
    for (int off = 32; off; off >>= 1)
        x += __shfl_xor(x, off);
    return x;
}

// Issue the 17 loads for absolute node nabs into (vv, sv). Pure issue; the
// consumer's first use triggers the waitcnt.
#define LOAD_NODE(vv, sv, nabs) do {                                          \
    const int n_ = (nabs);                                                    \
    const float* nbp_ = neigh_vecs + (size_t)n_ * (K * D) + 2 * lane;         \
    _Pragma("unroll")                                                         \
    for (int k = 0; k < K; ++k) vv[k] = *(const float2*)(nbp_ + (size_t)k * D); \
    sv = *(const float2*)(self_vecs + (size_t)n_ * D + 2 * lane);             \
} while (0)

// Two-pass softmax + context for the node in (vv, sv); writes Ct[buf][row].
#define CTX_NODE(vv, sv, row) do {                                            \
    float ss_ = sv.x * sv.x + sv.y * sv.y;                                    \
    float sc_[K];                                                             \
    _Pragma("unroll")                                                         \
    for (int k = 0; k < K; ++k) sc_[k] = sv.x * vv[k].x + sv.y * vv[k].y;     \
    ss_ = wave_allsum(ss_);                                                   \
    _Pragma("unroll")                                                         \
    for (int k = 0; k < K; ++k) sc_[k] = wave_allsum(sc_[k]);                 \
    float m_ = ss_;                                                           \
    _Pragma("unroll")                                                         \
    for (int k = 0; k < K; ++k) m_ = fmaxf(m_, sc_[k]);                       \
    float e_ = __expf(ss_ - m_);                                              \
    float sum_ = e_, cx_ = e_ * sv.x, cy_ = e_ * sv.y;                        \
    _Pragma("unroll")                                                         \
    for (int k = 0; k < K; ++k) {                                             \
        const float ek_ = __expf(sc_[k] - m_);                                \
        sum_ += ek_; cx_ += ek_ * vv[k].x; cy_ += ek_ * vv[k].y;              \
    }                                                                         \
    const float inv_ = 1.f / sum_;                                            \
    *(float2*)&Ct[buf][row][2 * lane] = make_float2(cx_ * inv_, cy_ * inv_);  \
} while (0)

__launch_bounds__(256, 3)
__global__ void gat_fused(const float* __restrict__ self_vecs,
                          const float* __restrict__ neigh_vecs,
                          const float* __restrict__ W,
                          float* __restrict__ out,
                          int n_tiles) {
    __shared__ __align__(16) unsigned short Wt[DOUT][WT_PITCH];   // 34.8 KiB
    __shared__ __align__(16) float Ct[2][16][CT_PITCH];           // 16.5 KiB

    const int tid = threadIdx.x;

    // ---- stage W^T as bf16 (R10-verbatim) ----
    for (int e = tid; e < D * DOUT; e += blockDim.x) {
        const int k = e >> 7, m = e & 127;     // W row-major [k][dout]
        Wt[m][k] = f2bf(W[e]);
    }
    __syncthreads();

    const int lane = tid & 63;
    const int wid  = tid >> 6;
    const int nl   = lane & 15;   // node-in-tile / Wt row-in-subtile
    const int kb   = lane >> 4;   // k-subgroup (8 elems)
    const int r0   = wid * 4;     // this wave's first row in the tile

    float2 vA[K], vB[K], sA, sB;

    int buf = 0;
    int t = blockIdx.x;
    if (t < n_tiles) {                       // prologue: 2 nodes in flight
        LOAD_NODE(vA, sA, t * 16 + r0 + 0);
        LOAD_NODE(vB, sB, t * 16 + r0 + 1);
    }
    for (; t < n_tiles; t += gridDim.x, buf ^= 1) {
        const int node0 = t * 16;

        // ---- ctx, depth-2 pipelined: loads of node i+1 precede compute of i ----
        CTX_NODE(vA, sA, r0 + 0);
        LOAD_NODE(vA, sA, node0 + r0 + 2);
        CTX_NODE(vB, sB, r0 + 1);
        LOAD_NODE(vB, sB, node0 + r0 + 3);
        CTX_NODE(vA, sA, r0 + 2);
        CTX_NODE(vB, sB, r0 + 3);

        // ---- prefetch next tile's first 2 nodes: covers the MFMA bubble ----
        const int tn = t + gridDim.x;
        if (tn < n_tiles) {
            LOAD_NODE(vA, sA, tn * 16 + r0 + 0);
            LOAD_NODE(vB, sB, tn * 16 + r0 + 1);
        }

        __syncthreads();   // Ct[buf] complete (dbuf -> only barrier per tile)

        // ---- MFMA (R10-verbatim): this wave does nt = wid*2, wid*2+1 ----
        afrag acc[2];
        #pragma unroll
        for (int h = 0; h < 2; ++h)
            #pragma unroll
            for (int r4 = 0; r4 < 4; ++r4) acc[h][r4] = 0.f;

        #pragma unroll
        for (int kc = 0; kc < 4; ++kc) {
            const float* cp = &Ct[buf][nl][kc * 32 + kb * 8];
            const float4 c0 = *(const float4*)cp;
            const float4 c1 = *(const float4*)(cp + 4);
            const float cf[8] = {c0.x, c0.y, c0.z, c0.w, c1.x, c1.y, c1.z, c1.w};
            bfrag ch, cl;
            #pragma unroll
            for (int i = 0; i < 8; ++i) {
                const unsigned short hh = f2bf(cf[i]);
                ch[i] = (short)hh;
                cl[i] = (short)f2bf(cf[i] - bf2f(hh));
            }
            #pragma unroll
            for (int h = 0; h < 2; ++h) {
                const int nt = wid * 2 + h;
                const bfrag a = *(const bfrag*)&Wt[nt * 16 + nl][kc * 32 + kb * 8];
                acc[h] = __builtin_amdgcn_mfma_f32_16x16x32_bf16(a, ch, acc[h], 0, 0, 0);
                acc[h] = __builtin_amdgcn_mfma_f32_16x16x32_bf16(a, cl, acc[h], 0, 0, 0);
            }
        }
        // D: col=lane&15=node, row=(lane>>4)*4+r=outcol (m89-verified)
        float* orow = out + (size_t)(node0 + nl) * DOUT + kb * 4;
        #pragma unroll
        for (int h = 0; h < 2; ++h) {
            const int nt = wid * 2 + h;
            *(float4*)(orow + nt * 16) =
                make_float4(fmaxf(acc[h][0], 0.f), fmaxf(acc[h][1], 0.f),
                            fmaxf(acc[h][2], 0.f), fmaxf(acc[h][3], 0.f));
        }
    }
}

extern "C" void kernel_launch(void* const* d_in, const int* in_sizes, int n_in,
                              void* d_out, int out_size, void* d_ws, size_t ws_size,
                              hipStream_t stream) {
    const float* self_vecs = (const float*)d_in[0];
    const float* neigh     = (const float*)d_in[1];
    const float* W         = (const float*)d_in[2];
    float* out = (float*)d_out;

    const int n_nodes = in_sizes[0] / D;   // 100000
    const int n_tiles = n_nodes / 16;      // 6250 exact

    const int tpb = 256;     // 4 waves
    const int blocks = 768;  // 3 blocks/CU x 256 CU (51.3 KiB LDS each)
    gat_fused<<<dim3(blocks), dim3(tpb), 0, stream>>>(
        self_vecs, neigh, W, out, n_tiles);
}